// Round 4
// baseline (2149.929 us; speedup 1.0000x reference)
//
#include <hip/hip_runtime.h>
#include <hip/hip_bf16.h>
#include <stdint.h>

#define B_   256
#define T_   512
#define DIN  128
#define DST  128
#define DHID 512

typedef __attribute__((ext_vector_type(8))) short bf16x8;
typedef __attribute__((ext_vector_type(4))) float f32x4;

static __device__ __forceinline__ unsigned short f2bf(float f) {
    union { float f; unsigned int u; } v; v.f = f;
    unsigned int u = v.u;
    unsigned int rounding = 0x7FFFu + ((u >> 16) & 1u);
    u += rounding;
    return (unsigned short)(u >> 16);
}

template <typename T>
static __device__ __forceinline__ void keepreg(T& x) {
    asm volatile("" : "+v"(x));
}

static __device__ __forceinline__ void gload_lds16(const void* g, void* l) {
    __builtin_amdgcn_global_load_lds(
        (const __attribute__((address_space(1))) unsigned int*)g,
        (__attribute__((address_space(3))) unsigned int*)l,
        16, 0, 0);
}

__global__ void cvt_w1t(const float* __restrict__ w1, unsigned short* __restrict__ out) {
    int tid = blockIdx.x * blockDim.x + threadIdx.x;
    int n = tid >> 8;
    int k = tid & 255;
    out[tid] = f2bf(w1[k * DHID + n]);
}

__global__ void cvt_w2t(const float* __restrict__ w2, unsigned short* __restrict__ out) {
    int tid = blockIdx.x * blockDim.x + threadIdx.x;
    int n = tid >> 9;
    int h = tid & 511;
    out[tid] = f2bf(w2[h * DST + n]);
}

__global__ void cvt_x(const float* __restrict__ x, unsigned short* __restrict__ wsx) {
    int tid = blockIdx.x * blockDim.x + threadIdx.x;
    int q  = tid & 15;
    int t  = (tid >> 4) & 511;
    int br = tid >> 13;
    int g  = br >> 4, r = br & 15;
    const float* src = x + ((size_t)br * T_ + t) * DIN + q * 8;
    float4 p = *reinterpret_cast<const float4*>(src);
    float4 s = *reinterpret_cast<const float4*>(src + 4);
    union { bf16x8 v; unsigned short u[8]; } cv;
    cv.u[0] = f2bf(p.x); cv.u[1] = f2bf(p.y); cv.u[2] = f2bf(p.z); cv.u[3] = f2bf(p.w);
    cv.u[4] = f2bf(s.x); cv.u[5] = f2bf(s.y); cv.u[6] = f2bf(s.z); cv.u[7] = f2bf(s.w);
    size_t base = ((size_t)(g * T_ + t)) * 4096 + (size_t)r * 256 + (size_t)((q * 16) ^ ((r & 7) << 4));
    *reinterpret_cast<bf16x8*>((char*)wsx + base) = cv.v;
}

template<bool XLDS>
__global__ __launch_bounds__(512)
__attribute__((amdgpu_waves_per_eu(2, 2)))
void rnn_main(
    const float* __restrict__ x,
    const unsigned short* __restrict__ wsx,
    const unsigned short* __restrict__ w1t,
    const unsigned short* __restrict__ w2t,
    const float* __restrict__ a0,
    const float* __restrict__ b1,
    const float* __restrict__ b2,
    float* __restrict__ out)
{
    __shared__ unsigned short Hs[16 * DHID];
    __shared__ unsigned short a_bf[16 * DST];
    __shared__ unsigned short xbuf[2][16 * DIN];

    const int tid  = threadIdx.x;
    const int lane = tid & 63;
    const int w    = tid >> 6;
    const int bg   = blockIdx.x * 16;
    const int lr   = lane & 15;
    const int lg   = lane >> 4;
    const int swz  = (lr & 7) << 4;

    // ---- load all weights into registers ----
    bf16x8 W1f[4][8];   // 128 VGPR
#pragma unroll
    for (int j = 0; j < 4; ++j) {
        const unsigned short* wr = w1t + (size_t)(w * 64 + j * 16 + lr) * 256 + lg * 8;
#pragma unroll
        for (int kk = 0; kk < 8; ++kk)
            W1f[j][kk] = *reinterpret_cast<const bf16x8*>(wr + kk * 32);
    }
    bf16x8 W2f[8][2];   // 64 VGPR
    {
        const unsigned short* wr = w2t + (size_t)(w * 16 + lr) * 512 + lg * 8;
#pragma unroll
        for (int kk = 0; kk < 8; ++kk) {
            W2f[kk][0] = *reinterpret_cast<const bf16x8*>(wr + kk * 32);
            W2f[kk][1] = *reinterpret_cast<const bf16x8*>(wr + 256 + kk * 32);
        }
    }

    float a_reg[4];
#pragma unroll
    for (int r = 0; r < 4; ++r)
        a_reg[r] = a0[(size_t)(bg + lg * 4 + r) * DST + w * 16 + lr];
#pragma unroll
    for (int r = 0; r < 4; ++r) {
        int row = lg * 4 + r, col = w * 16 + lr;
        *(unsigned short*)((char*)a_bf + row * 256 + ((col * 2) ^ ((row & 7) << 4))) = f2bf(a_reg[r]);
    }

    float b1v[4];
#pragma unroll
    for (int j = 0; j < 4; ++j) b1v[j] = b1[w * 64 + j * 16 + lr];
    const float b2v = b2[w * 16 + lr];

    if constexpr (XLDS) {
        if (tid < 256) {
            const char* src = (const char*)wsx + (size_t)blockIdx.x * T_ * 4096 + (size_t)tid * 16;
            gload_lds16(src, (char*)&xbuf[0][0] + w * 1024);
        }
    }
    __syncthreads();

    f32x4 acc[4];
#pragma unroll
    for (int j = 0; j < 4; ++j) acc[j] = (f32x4)(0.0f);

    if constexpr (XLDS) {
#pragma unroll
        for (int kk = 0; kk < 4; ++kk) {
            bf16x8 xf = *reinterpret_cast<const bf16x8*>((const char*)&xbuf[0][0] + lr * 256 + ((kk * 64 + lg * 16) ^ swz));
#pragma unroll
            for (int j = 0; j < 4; ++j)
                acc[j] = __builtin_amdgcn_mfma_f32_16x16x32_bf16(xf, W1f[j][kk], acc[j], 0, 0, 0);
        }
    } else {
        const float* xr = x + (size_t)(bg + lr) * (T_ * DIN) + lg * 8;
#pragma unroll
        for (int kk = 0; kk < 4; ++kk) {
            float4 p = *reinterpret_cast<const float4*>(xr + kk * 32);
            float4 q = *reinterpret_cast<const float4*>(xr + kk * 32 + 4);
            union { bf16x8 v; unsigned short u[8]; } cv;
            cv.u[0] = f2bf(p.x); cv.u[1] = f2bf(p.y); cv.u[2] = f2bf(p.z); cv.u[3] = f2bf(p.w);
            cv.u[4] = f2bf(q.x); cv.u[5] = f2bf(q.y); cv.u[6] = f2bf(q.z); cv.u[7] = f2bf(q.w);
#pragma unroll
            for (int j = 0; j < 4; ++j)
                acc[j] = __builtin_amdgcn_mfma_f32_16x16x32_bf16(cv.v, W1f[j][kk], acc[j], 0, 0, 0);
        }
    }

    for (int t = 0; t < T_; ++t) {
        // ---- loop-carried opaque dependency: weights CANNOT be rematerialized ----
#pragma unroll
        for (int j = 0; j < 4; ++j)
#pragma unroll
            for (int kk = 0; kk < 8; ++kk)
                keepreg(W1f[j][kk]);
#pragma unroll
        for (int kk = 0; kk < 8; ++kk) {
            keepreg(W2f[kk][0]);
            keepreg(W2f[kk][1]);
        }

        // prefetch x(t+1)
        if constexpr (XLDS) {
            if (tid < 256) {
                int tn = (t + 1 < T_) ? t + 1 : T_ - 1;
                const char* src = (const char*)wsx + ((size_t)(blockIdx.x * T_ + tn)) * 4096 + (size_t)tid * 16;
                gload_lds16(src, (char*)&xbuf[(t + 1) & 1][0] + w * 1024);
            }
        }

        // a-part of GEMM1 (acc holds x-part already)
#pragma unroll
        for (int kk = 0; kk < 4; ++kk) {
            bf16x8 af = *reinterpret_cast<const bf16x8*>((const char*)a_bf + lr * 256 + ((kk * 64 + lg * 16) ^ swz));
#pragma unroll
            for (int j = 0; j < 4; ++j)
                acc[j] = __builtin_amdgcn_mfma_f32_16x16x32_bf16(af, W1f[j][4 + kk], acc[j], 0, 0, 0);
        }

        // tanh + H store
#pragma unroll
        for (int j = 0; j < 4; ++j) {
#pragma unroll
            for (int r = 0; r < 4; ++r) {
                float v = acc[j][r] + b1v[j];
                float e = __expf(2.0f * v);
                float th = 1.0f - 2.0f / (e + 1.0f);
                int row = lg * 4 + r;
                int col = w * 64 + j * 16 + lr;
                *(unsigned short*)((char*)Hs + row * 1024 + ((col * 2) ^ ((row & 7) << 4))) = f2bf(th);
            }
        }
        __syncthreads();   // barrier1: Hs visible; drains x prefetch

        // GEMM2
        f32x4 s0 = (f32x4)(0.0f), s1 = (f32x4)(0.0f);
#pragma unroll
        for (int kk = 0; kk < 8; ++kk) {
            bf16x8 h0 = *reinterpret_cast<const bf16x8*>((const char*)Hs + lr * 1024 + ((kk * 64 + lg * 16) ^ swz));
            bf16x8 h1 = *reinterpret_cast<const bf16x8*>((const char*)Hs + lr * 1024 + ((512 + kk * 64 + lg * 16) ^ swz));
            s0 = __builtin_amdgcn_mfma_f32_16x16x32_bf16(h0, W2f[kk][0], s0, 0, 0, 0);
            s1 = __builtin_amdgcn_mfma_f32_16x16x32_bf16(h1, W2f[kk][1], s1, 0, 0, 0);
        }

        // a += S + b2 ; publish bf16 state (s0/s1 die here, before x-part)
#pragma unroll
        for (int r = 0; r < 4; ++r) {
            float v = a_reg[r] + s0[r] + s1[r] + b2v;
            a_reg[r] = v;
            int row = lg * 4 + r, col = w * 16 + lr;
            *(unsigned short*)((char*)a_bf + row * 256 + ((col * 2) ^ ((row & 7) << 4))) = f2bf(v);
        }

        // x-part of GEMM1 for t+1
#pragma unroll
        for (int j = 0; j < 4; ++j) acc[j] = (f32x4)(0.0f);
        if constexpr (XLDS) {
            const char* xb = (const char*)&xbuf[(t + 1) & 1][0];
#pragma unroll
            for (int kk = 0; kk < 4; ++kk) {
                bf16x8 xf = *reinterpret_cast<const bf16x8*>(xb + lr * 256 + ((kk * 64 + lg * 16) ^ swz));
#pragma unroll
                for (int j = 0; j < 4; ++j)
                    acc[j] = __builtin_amdgcn_mfma_f32_16x16x32_bf16(xf, W1f[j][kk], acc[j], 0, 0, 0);
            }
        } else {
            int tn = (t + 1 < T_) ? t + 1 : T_ - 1;
            const float* xr = x + (size_t)(bg + lr) * (T_ * DIN) + (size_t)tn * DIN + lg * 8;
#pragma unroll
            for (int kk = 0; kk < 4; ++kk) {
                float4 p = *reinterpret_cast<const float4*>(xr + kk * 32);
                float4 q = *reinterpret_cast<const float4*>(xr + kk * 32 + 4);
                union { bf16x8 v; unsigned short u[8]; } cv;
                cv.u[0] = f2bf(p.x); cv.u[1] = f2bf(p.y); cv.u[2] = f2bf(p.z); cv.u[3] = f2bf(p.w);
                cv.u[4] = f2bf(q.x); cv.u[5] = f2bf(q.y); cv.u[6] = f2bf(q.z); cv.u[7] = f2bf(q.w);
#pragma unroll
                for (int j = 0; j < 4; ++j)
                    acc[j] = __builtin_amdgcn_mfma_f32_16x16x32_bf16(cv.v, W1f[j][kk], acc[j], 0, 0, 0);
            }
        }

        __syncthreads();   // barrier2: a_bf visible for next step's a-part
    }

#pragma unroll
    for (int r = 0; r < 4; ++r)
        out[(size_t)(bg + lg * 4 + r) * DST + w * 16 + lr] = a_reg[r];
}

extern "C" void kernel_launch(void* const* d_in, const int* in_sizes, int n_in,
                              void* d_out, int out_size, void* d_ws, size_t ws_size,
                              hipStream_t stream) {
    const float* x  = (const float*)d_in[0];
    const float* a0 = (const float*)d_in[1];
    const float* W1 = (const float*)d_in[2];
    const float* b1 = (const float*)d_in[3];
    const float* W2 = (const float*)d_in[4];
    const float* b2 = (const float*)d_in[5];

    unsigned short* w1t = (unsigned short*)d_ws;
    unsigned short* w2t = w1t + 512 * 256;
    unsigned short* wsx = w2t + 128 * 512;
    const size_t need = (size_t)384 * 1024 + (size_t)B_ * T_ * DIN * 2;

    cvt_w1t<<<512, 256, 0, stream>>>(W1, w1t);
    cvt_w2t<<<256, 256, 0, stream>>>(W2, w2t);

    if (ws_size >= need) {
        cvt_x<<<8192, 256, 0, stream>>>(x, wsx);
        rnn_main<true><<<16, 512, 0, stream>>>(x, wsx, w1t, w2t, a0, b1, b2, (float*)d_out);
    } else {
        rnn_main<false><<<16, 512, 0, stream>>>(x, wsx, w1t, w2t, a0, b1, b2, (float*)d_out);
    }
}

// Round 5
// 1464.889 us; speedup vs baseline: 1.4676x; 1.4676x over previous
//
#include <hip/hip_runtime.h>
#include <hip/hip_bf16.h>
#include <stdint.h>

#define B_   256
#define T_   512
#define DIN  128
#define DST  128
#define DHID 512

typedef __attribute__((ext_vector_type(8))) short bf16x8;
typedef __attribute__((ext_vector_type(4))) float f32x4;

static __device__ __forceinline__ unsigned short f2bf(float f) {
    union { float f; unsigned int u; } v; v.f = f;
    unsigned int u = v.u;
    unsigned int rounding = 0x7FFFu + ((u >> 16) & 1u);
    u += rounding;
    return (unsigned short)(u >> 16);
}

// ---- inline-asm MFMA: B operand pinned in AGPR ("a") or VGPR ("v") ----
// Chain head: C = literal 0 (no VALU zero-init, no VALU->MFMA SrcC hazard).
static __device__ __forceinline__ f32x4 mfma_a_first(bf16x8 a, bf16x8 b) {
    f32x4 d;
    asm("v_mfma_f32_16x16x32_bf16 %0, %1, %2, 0" : "=v"(d) : "v"(a), "a"(b));
    return d;
}
static __device__ __forceinline__ void mfma_a(f32x4& acc, bf16x8 a, bf16x8 b) {
    asm("v_mfma_f32_16x16x32_bf16 %0, %1, %2, %0" : "+v"(acc) : "v"(a), "a"(b));
}
// Chain tail: embedded s_nop 7 so a following VALU read of acc is safe.
static __device__ __forceinline__ void mfma_a_tail(f32x4& acc, bf16x8 a, bf16x8 b) {
    asm("v_mfma_f32_16x16x32_bf16 %0, %1, %2, %0\n\ts_nop 7" : "+v"(acc) : "v"(a), "a"(b));
}
static __device__ __forceinline__ f32x4 mfma_v_first(bf16x8 a, bf16x8 b) {
    f32x4 d;
    asm("v_mfma_f32_16x16x32_bf16 %0, %1, %2, 0" : "=v"(d) : "v"(a), "v"(b));
    return d;
}
static __device__ __forceinline__ void mfma_v(f32x4& acc, bf16x8 a, bf16x8 b) {
    asm("v_mfma_f32_16x16x32_bf16 %0, %1, %2, %0" : "+v"(acc) : "v"(a), "v"(b));
}
static __device__ __forceinline__ void mfma_v_tail(f32x4& acc, bf16x8 a, bf16x8 b) {
    asm("v_mfma_f32_16x16x32_bf16 %0, %1, %2, %0\n\ts_nop 7" : "+v"(acc) : "v"(a), "v"(b));
}

template <typename T>
static __device__ __forceinline__ void pin_agpr(T& x) {
    asm("" : "+a"(x));   // force live range into AGPR file
}

static __device__ __forceinline__ void gload_lds16(const void* g, void* l) {
    __builtin_amdgcn_global_load_lds(
        (const __attribute__((address_space(1))) unsigned int*)g,
        (__attribute__((address_space(3))) unsigned int*)l,
        16, 0, 0);
}

__global__ void cvt_w1t(const float* __restrict__ w1, unsigned short* __restrict__ out) {
    int tid = blockIdx.x * blockDim.x + threadIdx.x;
    int n = tid >> 8;
    int k = tid & 255;
    out[tid] = f2bf(w1[k * DHID + n]);
}

__global__ void cvt_w2t(const float* __restrict__ w2, unsigned short* __restrict__ out) {
    int tid = blockIdx.x * blockDim.x + threadIdx.x;
    int n = tid >> 9;
    int h = tid & 511;
    out[tid] = f2bf(w2[h * DST + n]);
}

__global__ void cvt_x(const float* __restrict__ x, unsigned short* __restrict__ wsx) {
    int tid = blockIdx.x * blockDim.x + threadIdx.x;
    int q  = tid & 15;
    int t  = (tid >> 4) & 511;
    int br = tid >> 13;
    int g  = br >> 4, r = br & 15;
    const float* src = x + ((size_t)br * T_ + t) * DIN + q * 8;
    float4 p = *reinterpret_cast<const float4*>(src);
    float4 s = *reinterpret_cast<const float4*>(src + 4);
    union { bf16x8 v; unsigned short u[8]; } cv;
    cv.u[0] = f2bf(p.x); cv.u[1] = f2bf(p.y); cv.u[2] = f2bf(p.z); cv.u[3] = f2bf(p.w);
    cv.u[4] = f2bf(s.x); cv.u[5] = f2bf(s.y); cv.u[6] = f2bf(s.z); cv.u[7] = f2bf(s.w);
    size_t base = ((size_t)(g * T_ + t)) * 4096 + (size_t)r * 256 + (size_t)((q * 16) ^ ((r & 7) << 4));
    *reinterpret_cast<bf16x8*>((char*)wsx + base) = cv.v;
}

template<bool XLDS>
__global__ __launch_bounds__(512)
__attribute__((amdgpu_waves_per_eu(2, 2)))
void rnn_main(
    const float* __restrict__ x,
    const unsigned short* __restrict__ wsx,
    const unsigned short* __restrict__ w1t,  // [512][256] bf16
    const unsigned short* __restrict__ w2t,  // [128][512] bf16
    const float* __restrict__ a0,
    const float* __restrict__ b1,
    const float* __restrict__ b2,
    float* __restrict__ out)
{
    __shared__ unsigned short W2s[128 * DHID / 1];   // 128 rows x 512 k -> 128 KB, swizzled
    __shared__ unsigned short Hs[16 * DHID];         // 16 KB, swizzled
    __shared__ unsigned short a_bf[16 * DST];        // 4 KB, swizzled
    __shared__ unsigned short xbuf[2][16 * DIN];     // 8 KB, swizzled

    const int tid  = threadIdx.x;
    const int lane = tid & 63;
    const int w    = tid >> 6;
    const int bg   = blockIdx.x * 16;
    const int lr   = lane & 15;
    const int lg   = lane >> 4;
    const int swz  = (lr & 7) << 4;

    // ---- W2 -> swizzled LDS (once) ----
#pragma unroll
    for (int i = 0; i < 16; ++i) {
        int idx = i * 512 + tid;          // 0..8191 (16B chunks)
        int row = idx >> 6;               // 0..127
        int cc  = idx & 63;
        bf16x8 v = *reinterpret_cast<const bf16x8*>(w2t + (size_t)row * 512 + cc * 8);
        int byte = row * 1024 + ((cc * 16) ^ ((row & 7) << 4));
        *reinterpret_cast<bf16x8*>((char*)W2s + byte) = v;
    }

    // ---- W1 fragments -> AGPRs (once). [j][kk]: kk 0..3 = x-part, 4..7 = a-part ----
    bf16x8 W1f[4][8];
#pragma unroll
    for (int j = 0; j < 4; ++j) {
        const unsigned short* wr = w1t + (size_t)(w * 64 + j * 16 + lr) * 256 + lg * 8;
#pragma unroll
        for (int kk = 0; kk < 8; ++kk) {
            W1f[j][kk] = *reinterpret_cast<const bf16x8*>(wr + kk * 32);
            pin_agpr(W1f[j][kk]);
        }
    }

    // ---- state: lane owns a[row=lg*4+r][col=w*16+lr] ----
    float a_reg[4];
#pragma unroll
    for (int r = 0; r < 4; ++r)
        a_reg[r] = a0[(size_t)(bg + lg * 4 + r) * DST + w * 16 + lr];
#pragma unroll
    for (int r = 0; r < 4; ++r) {
        int row = lg * 4 + r, col = w * 16 + lr;
        *(unsigned short*)((char*)a_bf + row * 256 + ((col * 2) ^ ((row & 7) << 4))) = f2bf(a_reg[r]);
    }

    float b1v[4];
#pragma unroll
    for (int j = 0; j < 4; ++j) b1v[j] = b1[w * 64 + j * 16 + lr];
    const float b2v = b2[w * 16 + lr];

    if constexpr (XLDS) {
        if (tid < 256) {
            const char* src = (const char*)wsx + (size_t)blockIdx.x * T_ * 4096 + (size_t)tid * 16;
            gload_lds16(src, (char*)&xbuf[0][0] + w * 1024);
        }
    }
    __syncthreads();   // W2s, a_bf, xbuf[0] visible; vmcnt drained

    // ---- prologue: x-part of GEMM1 for t=0 ----
    f32x4 acc[4];
    if constexpr (XLDS) {
#pragma unroll
        for (int kk = 0; kk < 4; ++kk) {
            bf16x8 xf = *reinterpret_cast<const bf16x8*>((const char*)&xbuf[0][0] + lr * 256 + ((kk * 64 + lg * 16) ^ swz));
#pragma unroll
            for (int j = 0; j < 4; ++j) {
                if (kk == 0) acc[j] = mfma_a_first(xf, W1f[j][0]);
                else         mfma_a(acc[j], xf, W1f[j][kk]);
            }
        }
    } else {
        const float* xr = x + (size_t)(bg + lr) * (T_ * DIN) + lg * 8;
#pragma unroll
        for (int j = 0; j < 4; ++j) acc[j] = (f32x4)(0.0f);
#pragma unroll
        for (int kk = 0; kk < 4; ++kk) {
            float4 p = *reinterpret_cast<const float4*>(xr + kk * 32);
            float4 q = *reinterpret_cast<const float4*>(xr + kk * 32 + 4);
            union { bf16x8 v; unsigned short u[8]; } cv;
            cv.u[0] = f2bf(p.x); cv.u[1] = f2bf(p.y); cv.u[2] = f2bf(p.z); cv.u[3] = f2bf(p.w);
            cv.u[4] = f2bf(q.x); cv.u[5] = f2bf(q.y); cv.u[6] = f2bf(q.z); cv.u[7] = f2bf(q.w);
#pragma unroll
            for (int j = 0; j < 4; ++j)
                acc[j] = __builtin_amdgcn_mfma_f32_16x16x32_bf16(cv.v, W1f[j][kk], acc[j], 0, 0, 0);
        }
    }

    for (int t = 0; t < T_; ++t) {
        // 0) prefetch x(t+1)
        if constexpr (XLDS) {
            if (tid < 256) {
                int tn = (t + 1 < T_) ? t + 1 : T_ - 1;
                const char* src = (const char*)wsx + ((size_t)(blockIdx.x * T_ + tn)) * 4096 + (size_t)tid * 16;
                gload_lds16(src, (char*)&xbuf[(t + 1) & 1][0] + w * 1024);
            }
        }

        // 1) a-part of GEMM1 (acc holds x-part); tails embed s_nop before tanh reads
#pragma unroll
        for (int kk = 0; kk < 4; ++kk) {
            bf16x8 af = *reinterpret_cast<const bf16x8*>((const char*)a_bf + lr * 256 + ((kk * 64 + lg * 16) ^ swz));
#pragma unroll
            for (int j = 0; j < 4; ++j) {
                if (kk == 3) mfma_a_tail(acc[j], af, W1f[j][4 + kk]);
                else         mfma_a(acc[j], af, W1f[j][4 + kk]);
            }
        }

        // 2) tanh + H store
#pragma unroll
        for (int j = 0; j < 4; ++j) {
#pragma unroll
            for (int r = 0; r < 4; ++r) {
                float v = acc[j][r] + b1v[j];
                float e = __expf(2.0f * v);
                float th = 1.0f - 2.0f / (e + 1.0f);
                int row = lg * 4 + r;
                int col = w * 64 + j * 16 + lr;
                *(unsigned short*)((char*)Hs + row * 1024 + ((col * 2) ^ ((row & 7) << 4))) = f2bf(th);
            }
        }
        __syncthreads();   // barrier1: Hs visible; x prefetch drained

        // 3) GEMM2: wave w -> cols 16w..16w+16; W2 frags from swizzled LDS
        f32x4 s0, s1;
        {
            const char* w2b = (const char*)W2s + (w * 16 + lr) * 1024;  // (row&7)==(lr&7) -> same swz
            const char* hb  = (const char*)Hs + lr * 1024;
#pragma unroll
            for (int kk = 0; kk < 8; ++kk) {
                int c0 = (kk * 64 + lg * 16) ^ swz;
                int c1 = (512 + kk * 64 + lg * 16) ^ swz;
                bf16x8 h0 = *reinterpret_cast<const bf16x8*>(hb + c0);
                bf16x8 h1 = *reinterpret_cast<const bf16x8*>(hb + c1);
                bf16x8 g0 = *reinterpret_cast<const bf16x8*>(w2b + c0);
                bf16x8 g1 = *reinterpret_cast<const bf16x8*>(w2b + c1);
                if (kk == 0)      { s0 = mfma_v_first(h0, g0);  s1 = mfma_v_first(h1, g1); }
                else if (kk == 7) { mfma_v_tail(s0, h0, g0);    mfma_v_tail(s1, h1, g1);  }
                else              { mfma_v(s0, h0, g0);         mfma_v(s1, h1, g1);       }
            }
        }

        // 4) a += S + b2 ; publish bf16 state
#pragma unroll
        for (int r = 0; r < 4; ++r) {
            float v = a_reg[r] + s0[r] + s1[r] + b2v;
            a_reg[r] = v;
            int row = lg * 4 + r, col = w * 16 + lr;
            *(unsigned short*)((char*)a_bf + row * 256 + ((col * 2) ^ ((row & 7) << 4))) = f2bf(v);
        }

        // 5) x-part of GEMM1 for t+1 (chain heads use C=0 literal -> no zero-init VALU)
        if constexpr (XLDS) {
            const char* xb = (const char*)&xbuf[(t + 1) & 1][0];
#pragma unroll
            for (int kk = 0; kk < 4; ++kk) {
                bf16x8 xf = *reinterpret_cast<const bf16x8*>(xb + lr * 256 + ((kk * 64 + lg * 16) ^ swz));
#pragma unroll
                for (int j = 0; j < 4; ++j) {
                    if (kk == 0) acc[j] = mfma_a_first(xf, W1f[j][0]);
                    else         mfma_a(acc[j], xf, W1f[j][kk]);
                }
            }
        } else {
            int tn = (t + 1 < T_) ? t + 1 : T_ - 1;
            const float* xr = x + (size_t)(bg + lr) * (T_ * DIN) + (size_t)tn * DIN + lg * 8;
#pragma unroll
            for (int j = 0; j < 4; ++j) acc[j] = (f32x4)(0.0f);
#pragma unroll
            for (int kk = 0; kk < 4; ++kk) {
                float4 p = *reinterpret_cast<const float4*>(xr + kk * 32);
                float4 q = *reinterpret_cast<const float4*>(xr + kk * 32 + 4);
                union { bf16x8 v; unsigned short u[8]; } cv;
                cv.u[0] = f2bf(p.x); cv.u[1] = f2bf(p.y); cv.u[2] = f2bf(p.z); cv.u[3] = f2bf(p.w);
                cv.u[4] = f2bf(q.x); cv.u[5] = f2bf(q.y); cv.u[6] = f2bf(q.z); cv.u[7] = f2bf(q.w);
#pragma unroll
                for (int j = 0; j < 4; ++j)
                    acc[j] = __builtin_amdgcn_mfma_f32_16x16x32_bf16(cv.v, W1f[j][kk], acc[j], 0, 0, 0);
            }
        }

        __syncthreads();   // barrier2: a_bf visible for next iteration
    }

#pragma unroll
    for (int r = 0; r < 4; ++r)
        out[(size_t)(bg + lg * 4 + r) * DST + w * 16 + lr] = a_reg[r];
}

extern "C" void kernel_launch(void* const* d_in, const int* in_sizes, int n_in,
                              void* d_out, int out_size, void* d_ws, size_t ws_size,
                              hipStream_t stream) {
    const float* x  = (const float*)d_in[0];
    const float* a0 = (const float*)d_in[1];
    const float* W1 = (const float*)d_in[2];
    const float* b1 = (const float*)d_in[3];
    const float* W2 = (const float*)d_in[4];
    const float* b2 = (const float*)d_in[5];

    unsigned short* w1t = (unsigned short*)d_ws;
    unsigned short* w2t = w1t + 512 * 256;
    unsigned short* wsx = w2t + 128 * 512;
    const size_t need = (size_t)384 * 1024 + (size_t)B_ * T_ * DIN * 2;

    cvt_w1t<<<512, 256, 0, stream>>>(W1, w1t);
    cvt_w2t<<<256, 256, 0, stream>>>(W2, w2t);

    if (ws_size >= need) {
        cvt_x<<<8192, 256, 0, stream>>>(x, wsx);
        rnn_main<true><<<16, 512, 0, stream>>>(x, wsx, w1t, w2t, a0, b1, b2, (float*)d_out);
    } else {
        rnn_main<false><<<16, 512, 0, stream>>>(x, wsx, w1t, w2t, a0, b1, b2, (float*)d_out);
    }
}